// Round 6
// baseline (229.009 us; speedup 1.0000x reference)
//
#include <hip/hip_runtime.h>
#include <hip/hip_bf16.h>

#define N_ROWS 4096
#define TWO_N 8192
#define DIM 512
#define INV_T 14.285714285714286f          // 1/0.07
#define LOG2E 1.4426950408889634f
#define C_LOG2E 20.60992915555662f          // (1/0.07)*log2(e)
#define INV_SQRT_T 3.7796447300922722f      // 1/sqrt(0.07)

typedef __bf16 bf16x8 __attribute__((ext_vector_type(8)));
typedef float f32x4 __attribute__((ext_vector_type(4)));

// Vectorized prep: 2048 blocks, 2 rows per block (one z1/z2 pair handled by
// each 128-thread half). float4 loads, uint2 (4xbf16) stores.
// Also zeroes rowsum.
__global__ void k_prep(const float* __restrict__ z1, const float* __restrict__ z2,
                       __hip_bfloat16* __restrict__ zn, float* __restrict__ posbuf,
                       float* __restrict__ rowsum) {
  __shared__ float red[4][3];
  const int t = threadIdx.x;
  if (blockIdx.x < 32) rowsum[blockIdx.x * 256 + t] = 0.f;
  const int half = t >> 7;              // 0 or 1
  const int tt = t & 127;
  const int r = blockIdx.x * 2 + half;
  const float4 a = *reinterpret_cast<const float4*>(z1 + (size_t)r * DIM + tt * 4);
  const float4 b = *reinterpret_cast<const float4*>(z2 + (size_t)r * DIM + tt * 4);
  float s1 = a.x * a.x + a.y * a.y + a.z * a.z + a.w * a.w;
  float s2 = b.x * b.x + b.y * b.y + b.z * b.z + b.w * b.w;
  float sd = a.x * b.x + a.y * b.y + a.z * b.z + a.w * b.w;
#pragma unroll
  for (int off = 32; off > 0; off >>= 1) {
    s1 += __shfl_down(s1, off, 64);
    s2 += __shfl_down(s2, off, 64);
    sd += __shfl_down(sd, off, 64);
  }
  const int w = t >> 6;
  if ((t & 63) == 0) { red[w][0] = s1; red[w][1] = s2; red[w][2] = sd; }
  __syncthreads();
  s1 = red[2 * half][0] + red[2 * half + 1][0];
  s2 = red[2 * half][1] + red[2 * half + 1][1];
  sd = red[2 * half][2] + red[2 * half + 1][2];
  const float sc1 = INV_SQRT_T / fmaxf(sqrtf(s1), 1e-8f);
  const float sc2 = INV_SQRT_T / fmaxf(sqrtf(s2), 1e-8f);
  union { __hip_bfloat16 h[4]; uint2 u; } p;
  p.h[0] = __float2bfloat16(a.x * sc1); p.h[1] = __float2bfloat16(a.y * sc1);
  p.h[2] = __float2bfloat16(a.z * sc1); p.h[3] = __float2bfloat16(a.w * sc1);
  *reinterpret_cast<uint2*>(zn + (size_t)r * DIM + tt * 4) = p.u;
  p.h[0] = __float2bfloat16(b.x * sc2); p.h[1] = __float2bfloat16(b.y * sc2);
  p.h[2] = __float2bfloat16(b.z * sc2); p.h[3] = __float2bfloat16(b.w * sc2);
  *reinterpret_cast<uint2*>(zn + (size_t)(r + N_ROWS) * DIM + tt * 4) = p.u;
  if (tt == 0) posbuf[r] = sd * sc1 * sc2;   // = cos(z1_r,z2_r)/T
}

// Barrier-free streaming flash-LSE GEMM.
// Block tile 256x128; 4 waves as 2x2, each wave 128x64 (8x4 frags of 16x16x32).
// Fragments loaded DIRECTLY from global (L2/L3-resident Zn), no LDS, no
// __syncthreads -> compiler software-pipelines loads with vmcnt(N), never 0.
// Triangle: keep element e only if gcol > grow (each unordered pair computed
// exactly once), add to rowsum[grow] and rowsum[gcol]. Diagonal auto-masked.
__global__ __launch_bounds__(256, 2) void k_lse(const __hip_bfloat16* __restrict__ Zn,
                                                float* __restrict__ rowsum) {
  const int rt = blockIdx.y;             // 0..31 (256-row tiles)
  const int ct = blockIdx.x;             // 0..63 (128-col tiles)
  if (ct < 2 * rt) return;               // strictly-lower tiles: no j>i elems

  const int tid  = threadIdx.x;
  const int wave = tid >> 6;
  const int lane = tid & 63;
  const int cl   = lane & 15;
  const int q    = lane >> 4;
  const int rowbase = rt * 256 + (wave >> 1) * 128;
  const int colbase = ct * 128 + (wave & 1) * 64;

  // lane's base pointers: row (base + frag*16 + cl), k-granule q*8
  const __hip_bfloat16* Ap = Zn + (size_t)(rowbase + cl) * DIM + q * 8;
  const __hip_bfloat16* Bp = Zn + (size_t)(colbase + cl) * DIM + q * 8;

  f32x4 acc[8][4] = {};

#pragma unroll 2
  for (int ks = 0; ks < DIM / 32; ks++) {
    const int ko = ks * 32;
    bf16x8 af[8], bfr[4];
#pragma unroll
    for (int i = 0; i < 8; i++)
      af[i] = *reinterpret_cast<const bf16x8*>(Ap + (size_t)(i * 16) * DIM + ko);
#pragma unroll
    for (int j = 0; j < 4; j++)
      bfr[j] = *reinterpret_cast<const bf16x8*>(Bp + (size_t)(j * 16) * DIM + ko);
#pragma unroll
    for (int i = 0; i < 8; i++)
#pragma unroll
      for (int j = 0; j < 4; j++)
        acc[i][j] = __builtin_amdgcn_mfma_f32_16x16x32_bf16(af[i], bfr[j], acc[i][j], 0, 0, 0);
  }

  // Epilogue. C-layout: col = cl, row = q*4 + r within each 16x16 frag.
  float psum[8][4];
#pragma unroll
  for (int i = 0; i < 8; i++)
#pragma unroll
    for (int r = 0; r < 4; r++) psum[i][r] = 0.f;
  float colp[4] = {0.f, 0.f, 0.f, 0.f};

#pragma unroll
  for (int i = 0; i < 8; i++) {
    const int gi = rowbase + i * 16 + q * 4;
#pragma unroll
    for (int j = 0; j < 4; j++) {
      const int gj = colbase + j * 16 + cl;
#pragma unroll
      for (int r = 0; r < 4; r++) {
        float e = exp2f(fmaf(acc[i][j][r], LOG2E, -C_LOG2E));
        e = (gj > gi + r) ? e : 0.f;      // strict upper triangle only
        psum[i][r] += e;
        colp[j] += e;
      }
    }
  }

  // row sums -> rowsum[grow] (reduce across cl lanes)
#pragma unroll
  for (int i = 0; i < 8; i++)
#pragma unroll
    for (int r = 0; r < 4; r++) {
      float v = psum[i][r];
      v += __shfl_xor(v, 1, 64);
      v += __shfl_xor(v, 2, 64);
      v += __shfl_xor(v, 4, 64);
      v += __shfl_xor(v, 8, 64);
      if (cl == 0) atomicAdd(&rowsum[rowbase + i * 16 + q * 4 + r], v);
    }

  // col sums -> rowsum[gcol] (reduce across q lanes)
#pragma unroll
  for (int j = 0; j < 4; j++) {
    float v = colp[j];
    v += __shfl_xor(v, 16, 64);
    v += __shfl_xor(v, 32, 64);
    if (q == 0) atomicAdd(&rowsum[colbase + j * 16 + cl], v);
  }
}

// Single-kernel finalize: 1024 threads, 8 rows each.
__global__ void k_final(const float* __restrict__ rowsum, const float* __restrict__ posbuf,
                        float* __restrict__ out) {
  __shared__ float red[16];
  const int t = threadIdx.x;
  float s = 0.f;
#pragma unroll
  for (int r = t; r < TWO_N; r += 1024) s += logf(rowsum[r]);
#pragma unroll
  for (int r = t; r < N_ROWS; r += 1024) s -= 2.f * posbuf[r];
#pragma unroll
  for (int off = 32; off > 0; off >>= 1) s += __shfl_down(s, off, 64);
  if ((t & 63) == 0) red[t >> 6] = s;
  __syncthreads();
  if (t == 0) {
    float tot = 0.f;
#pragma unroll
    for (int w = 0; w < 16; w++) tot += red[w];
    out[0] = tot / (float)TWO_N + INV_T;
  }
}

extern "C" void kernel_launch(void* const* d_in, const int* in_sizes, int n_in,
                              void* d_out, int out_size, void* d_ws, size_t ws_size,
                              hipStream_t stream) {
  const float* z1 = (const float*)d_in[0];
  const float* z2 = (const float*)d_in[1];
  float* out = (float*)d_out;
  char* ws = (char*)d_ws;

  __hip_bfloat16* zn = (__hip_bfloat16*)ws;              // 8192*512*2 = 8388608 B
  float* rowsum = (float*)(ws + 8388608);                 // 8192*4 = 32768 B
  float* posbuf = (float*)(ws + 8421376);                 // 4096*4 = 16384 B

  k_prep<<<2048, 256, 0, stream>>>(z1, z2, zn, posbuf, rowsum);
  k_lse<<<dim3(64, 32), 256, 0, stream>>>(zn, rowsum);
  k_final<<<1, 1024, 0, stream>>>(rowsum, posbuf, out);
}

// Round 7
// 222.326 us; speedup vs baseline: 1.0301x; 1.0301x over previous
//
#include <hip/hip_runtime.h>
#include <hip/hip_bf16.h>

#define N_ROWS 4096
#define TWO_N 8192
#define DIM 512
#define NBLK 1056
#define INV_T 14.285714285714286f          // 1/0.07
#define LOG2E 1.4426950408889634f
#define C_LOG2E 20.60992915555662f          // (1/0.07)*log2(e)
#define INV_SQRT_T 3.7796447300922722f      // 1/sqrt(0.07)

typedef __bf16 bf16x8 __attribute__((ext_vector_type(8)));
typedef float f32x4 __attribute__((ext_vector_type(4)));

#define ASYNC_COPY16(gp, lp)                                                     \
  __builtin_amdgcn_global_load_lds((const __attribute__((address_space(1))) void*)(gp), \
                                   (__attribute__((address_space(3))) void*)(lp), 16, 0, 0)

// Vectorized prep: 2048 blocks, 2 rows per block. float4 loads, uint2 stores.
// Also zeroes rowsum and the completion counter.
__global__ void k_prep(const float* __restrict__ z1, const float* __restrict__ z2,
                       __hip_bfloat16* __restrict__ zn, float* __restrict__ posbuf,
                       float* __restrict__ rowsum, unsigned int* __restrict__ ctr) {
  __shared__ float red[4][3];
  const int t = threadIdx.x;
  if (blockIdx.x < 32) rowsum[blockIdx.x * 256 + t] = 0.f;
  if (blockIdx.x == 0 && t == 0) ctr[0] = 0u;
  const int half = t >> 7;              // 0 or 1
  const int tt = t & 127;
  const int r = blockIdx.x * 2 + half;
  const float4 a = *reinterpret_cast<const float4*>(z1 + (size_t)r * DIM + tt * 4);
  const float4 b = *reinterpret_cast<const float4*>(z2 + (size_t)r * DIM + tt * 4);
  float s1 = a.x * a.x + a.y * a.y + a.z * a.z + a.w * a.w;
  float s2 = b.x * b.x + b.y * b.y + b.z * b.z + b.w * b.w;
  float sd = a.x * b.x + a.y * b.y + a.z * b.z + a.w * b.w;
#pragma unroll
  for (int off = 32; off > 0; off >>= 1) {
    s1 += __shfl_down(s1, off, 64);
    s2 += __shfl_down(s2, off, 64);
    sd += __shfl_down(sd, off, 64);
  }
  const int w = t >> 6;
  if ((t & 63) == 0) { red[w][0] = s1; red[w][1] = s2; red[w][2] = sd; }
  __syncthreads();
  s1 = red[2 * half][0] + red[2 * half + 1][0];
  s2 = red[2 * half][1] + red[2 * half + 1][1];
  sd = red[2 * half][2] + red[2 * half + 1][2];
  const float sc1 = INV_SQRT_T / fmaxf(sqrtf(s1), 1e-8f);
  const float sc2 = INV_SQRT_T / fmaxf(sqrtf(s2), 1e-8f);
  union { __hip_bfloat16 h[4]; uint2 u; } p;
  p.h[0] = __float2bfloat16(a.x * sc1); p.h[1] = __float2bfloat16(a.y * sc1);
  p.h[2] = __float2bfloat16(a.z * sc1); p.h[3] = __float2bfloat16(a.w * sc1);
  *reinterpret_cast<uint2*>(zn + (size_t)r * DIM + tt * 4) = p.u;
  p.h[0] = __float2bfloat16(b.x * sc2); p.h[1] = __float2bfloat16(b.y * sc2);
  p.h[2] = __float2bfloat16(b.z * sc2); p.h[3] = __float2bfloat16(b.w * sc2);
  *reinterpret_cast<uint2*>(zn + (size_t)(r + N_ROWS) * DIM + tt * 4) = p.u;
  if (tt == 0) posbuf[r] = sd * sc1 * sc2;   // = cos(z1_r,z2_r)/T
}

// Flash-LSE GEMM, 256x128 block tile over the strict upper triangle.
// 4 waves in 2x2; each wave 128x64 (8x4 frags of 16x16x32 bf16).
// LDS double-buffered staging via global_load_lds (k-granule rotation swizzle).
// Element mask gj>gi covers every unordered pair exactly once; each element
// feeds rowsum[gi] (row side) and rowsum[gj] (col side).
// Last block (atomic counter) performs the final log/pos reduction.
__global__ __launch_bounds__(256, 2) void k_lse(const __hip_bfloat16* __restrict__ Zn,
                                                float* __restrict__ rowsum,
                                                const float* __restrict__ posbuf,
                                                unsigned int* __restrict__ ctr,
                                                float* __restrict__ out) {
  __shared__ char smem[49152] __attribute__((aligned(16)));
  const int tid  = threadIdx.x;
  const int wave = tid >> 6;
  const int lane = tid & 63;
  const int cl   = lane & 15;
  const int q    = lane >> 4;

  // linear b -> (rt, ct): row rt holds tiles ct = 2rt..63; offset(rt)=rt*(65-rt)
  const int b = blockIdx.x;
  int rt = (int)((65.0f - sqrtf(4225.0f - 4.0f * (float)b)) * 0.5f);
  if (rt < 0) rt = 0;
  if (rt > 31) rt = 31;
  while (rt > 0 && rt * (65 - rt) > b) rt--;
  while ((rt + 1) * (65 - (rt + 1)) <= b) rt++;
  const int ct = 2 * rt + (b - rt * (65 - rt));

  // staging: A tile 256x32 (16KB, 1024 granules), B tile 128x32 (8KB, 512).
  // slot s holds granule (row=s>>2, kq = ((s&3) - ((s>>4)&3)) & 3).
  size_t ga[4], gb[2];
#pragma unroll
  for (int k2 = 0; k2 < 4; k2++) {
    const int s = tid + k2 * 256;
    const int r = s >> 2;
    const int kq = ((s & 3) - ((s >> 4) & 3)) & 3;
    ga[k2] = (size_t)(rt * 256 + r) * DIM + kq * 8;
  }
#pragma unroll
  for (int k2 = 0; k2 < 2; k2++) {
    const int s = tid + k2 * 256;
    const int r = s >> 2;
    const int kq = ((s & 3) - ((s >> 4) & 3)) & 3;
    gb[k2] = (size_t)(ct * 128 + r) * DIM + kq * 8;
  }

  f32x4 acc[8][4] = {};
  const int kx   = ((q + (cl >> 2)) & 3) * 16;      // byte offset of k-granule
  const int arow = (wave >> 1) * 128 + cl;          // + i*16, LDS row of A frag
  const int brow = (wave & 1) * 64 + cl;            // + j*16, LDS row of B frag

#define STAGE(bufi, ko)                                                        \
  {                                                                            \
    char* base = smem + (bufi) * 24576 + wave * 1024;                          \
    ASYNC_COPY16(Zn + ga[0] + (ko), base);                                     \
    ASYNC_COPY16(Zn + ga[1] + (ko), base + 4096);                              \
    ASYNC_COPY16(Zn + ga[2] + (ko), base + 8192);                              \
    ASYNC_COPY16(Zn + ga[3] + (ko), base + 12288);                             \
    ASYNC_COPY16(Zn + gb[0] + (ko), base + 16384);                             \
    ASYNC_COPY16(Zn + gb[1] + (ko), base + 20480);                             \
  }

  STAGE(0, 0);
  for (int ks = 0; ks < DIM / 32; ks++) {
    const int cur = ks & 1;
    __syncthreads();                      // drains copy issued last iteration
    if (ks + 1 < DIM / 32) STAGE(1 - cur, (ks + 1) * 32);

    const char* sb = smem + cur * 24576;
    bf16x8 af[8], bfr[4];
#pragma unroll
    for (int i = 0; i < 8; i++)
      af[i] = *reinterpret_cast<const bf16x8*>(sb + (arow + i * 16) * 64 + kx);
#pragma unroll
    for (int j = 0; j < 4; j++)
      bfr[j] = *reinterpret_cast<const bf16x8*>(sb + 16384 + (brow + j * 16) * 64 + kx);
#pragma unroll
    for (int i = 0; i < 8; i++)
#pragma unroll
      for (int j = 0; j < 4; j++)
        acc[i][j] = __builtin_amdgcn_mfma_f32_16x16x32_bf16(af[i], bfr[j], acc[i][j], 0, 0, 0);
  }
#undef STAGE

  // Epilogue. C-layout: col = cl, row = q*4 + r within each 16x16 frag.
  const int gibase = rt * 256 + (wave >> 1) * 128 + q * 4;
  const int gjbase = ct * 128 + (wave & 1) * 64 + cl;
  float psum[8][4];
#pragma unroll
  for (int i = 0; i < 8; i++)
#pragma unroll
    for (int r = 0; r < 4; r++) psum[i][r] = 0.f;
  float colp[4] = {0.f, 0.f, 0.f, 0.f};

#pragma unroll
  for (int i = 0; i < 8; i++) {
#pragma unroll
    for (int j = 0; j < 4; j++) {
      const int gj = gjbase + j * 16;
#pragma unroll
      for (int r = 0; r < 4; r++) {
        float e = exp2f(fmaf(acc[i][j][r], LOG2E, -C_LOG2E));
        e = (gj > gibase + i * 16 + r) ? e : 0.f;   // strict upper triangle
        psum[i][r] += e;
        colp[j] += e;
      }
    }
  }

  // row sums -> rowsum[gi] (reduce across cl lanes)
#pragma unroll
  for (int i = 0; i < 8; i++)
#pragma unroll
    for (int r = 0; r < 4; r++) {
      float v = psum[i][r];
      v += __shfl_xor(v, 1, 64);
      v += __shfl_xor(v, 2, 64);
      v += __shfl_xor(v, 4, 64);
      v += __shfl_xor(v, 8, 64);
      if (cl == 0) atomicAdd(&rowsum[gibase + i * 16 + r], v);
    }

  // col sums -> rowsum[gj] (reduce across q lanes)
#pragma unroll
  for (int j = 0; j < 4; j++) {
    float v = colp[j];
    v += __shfl_xor(v, 16, 64);
    v += __shfl_xor(v, 32, 64);
    if (q == 0) atomicAdd(&rowsum[gjbase + j * 16], v);
  }

  // ---- fused finalize: last block reduces ----
  __threadfence();
  __syncthreads();
  __shared__ int is_last;
  if (tid == 0) {
    unsigned int prev = __hip_atomic_fetch_add(ctr, 1u, __ATOMIC_ACQ_REL,
                                               __HIP_MEMORY_SCOPE_AGENT);
    is_last = (prev == NBLK - 1) ? 1 : 0;
  }
  __syncthreads();
  if (is_last) {
    float s = 0.f;
    for (int r = tid; r < TWO_N; r += 256) {
      float v = __hip_atomic_load(&rowsum[r], __ATOMIC_RELAXED,
                                  __HIP_MEMORY_SCOPE_AGENT);
      s += logf(v);
    }
    for (int r = tid; r < N_ROWS; r += 256) s -= 2.f * posbuf[r];
#pragma unroll
    for (int off = 32; off > 0; off >>= 1) s += __shfl_down(s, off, 64);
    float* red = reinterpret_cast<float*>(smem);
    if ((tid & 63) == 0) red[tid >> 6] = s;
    __syncthreads();
    if (tid == 0)
      out[0] = (red[0] + red[1] + red[2] + red[3]) / (float)TWO_N + INV_T;
  }
}

extern "C" void kernel_launch(void* const* d_in, const int* in_sizes, int n_in,
                              void* d_out, int out_size, void* d_ws, size_t ws_size,
                              hipStream_t stream) {
  const float* z1 = (const float*)d_in[0];
  const float* z2 = (const float*)d_in[1];
  float* out = (float*)d_out;
  char* ws = (char*)d_ws;

  __hip_bfloat16* zn = (__hip_bfloat16*)ws;              // 8192*512*2 = 8388608 B
  float* rowsum = (float*)(ws + 8388608);                 // 8192*4 = 32768 B
  float* posbuf = (float*)(ws + 8421376);                 // 4096*4 = 16384 B
  unsigned int* ctr = (unsigned int*)(ws + 8437760);      // 4 B

  k_prep<<<2048, 256, 0, stream>>>(z1, z2, zn, posbuf, rowsum, ctr);
  k_lse<<<NBLK, 256, 0, stream>>>(zn, rowsum, posbuf, ctr, out);
}